// Round 3
// baseline (1363.003 us; speedup 1.0000x reference)
//
#include <hip/hip_runtime.h>
#include <stdint.h>

// Problem constants
#define BB 64
#define LL 1024
#define DD 1024
#define CC 128
#define STOPTAG 127

// ---------------------------------------------------------------------------
// K1: emis[b*L + l][c] = sum_k x[.][k] * W[k][c] + bias[c]   (pure f32)
// Tile: 128 rows x 128 cols per block, BK=32, 256 threads, 8x8 micro-tile.
// A staged transposed in LDS; W read per-thread from global (L1/L2 resident).
// ---------------------------------------------------------------------------
__global__ __launch_bounds__(256) void k_emis(const float* __restrict__ x,
                                              const float* __restrict__ W,
                                              const float* __restrict__ bias,
                                              float* __restrict__ emis) {
    __shared__ float a_t[32][132];   // [k][row], stride 132 -> 528B rows (16B aligned)
    const int tid = threadIdx.x;
    const int bm  = blockIdx.x;                  // block of 128 rows
    const float* A = x + (size_t)bm * 128 * DD;
    const int tx = tid & 15, ty = tid >> 4;
    const int r0 = ty * 8, c0 = tx * 8;

    float acc[8][8];
#pragma unroll
    for (int i = 0; i < 8; ++i)
#pragma unroll
        for (int j = 0; j < 8; ++j) acc[i][j] = 0.0f;

    for (int kc = 0; kc < 32; ++kc) {
        __syncthreads();   // WAR on a_t
#pragma unroll
        for (int i = 0; i < 4; ++i) {
            int s   = tid + 256 * i;
            int row = s >> 3;
            int k0  = (s & 7) * 4;
            float4 v = *(const float4*)(A + (size_t)row * DD + kc * 32 + k0);
            a_t[k0 + 0][row] = v.x;
            a_t[k0 + 1][row] = v.y;
            a_t[k0 + 2][row] = v.z;
            a_t[k0 + 3][row] = v.w;
        }
        __syncthreads();
        const float* Wp = W + (size_t)kc * 32 * CC;
#pragma unroll
        for (int k = 0; k < 32; ++k) {
            float4 w0 = *(const float4*)(Wp + k * CC + c0);
            float4 w1 = *(const float4*)(Wp + k * CC + c0 + 4);
            float4 pa = *(const float4*)&a_t[k][r0];
            float4 pb = *(const float4*)&a_t[k][r0 + 4];
            float av[8] = {pa.x, pa.y, pa.z, pa.w, pb.x, pb.y, pb.z, pb.w};
            float wv[8] = {w0.x, w0.y, w0.z, w0.w, w1.x, w1.y, w1.z, w1.w};
#pragma unroll
            for (int i = 0; i < 8; ++i)
#pragma unroll
                for (int j = 0; j < 8; ++j)
                    acc[i][j] = fmaf(av[i], wv[j], acc[i][j]);
        }
    }
    float4 bv0 = *(const float4*)(bias + c0);
    float4 bv1 = *(const float4*)(bias + c0 + 4);
    float bb[8] = {bv0.x, bv0.y, bv0.z, bv0.w, bv1.x, bv1.y, bv1.z, bv1.w};
#pragma unroll
    for (int i = 0; i < 8; ++i) {
        size_t row = (size_t)bm * 128 + r0 + i;
        float4 o0 = make_float4(acc[i][0] + bb[0], acc[i][1] + bb[1],
                                acc[i][2] + bb[2], acc[i][3] + bb[3]);
        float4 o1 = make_float4(acc[i][4] + bb[4], acc[i][5] + bb[5],
                                acc[i][6] + bb[6], acc[i][7] + bb[7]);
        *(float4*)(emis + row * CC + c0)     = o0;
        *(float4*)(emis + row * CC + c0 + 4) = o1;
    }
}

// ---------------------------------------------------------------------------
// Mask may arrive as 1-byte bool or widened int32. Discriminator: byte [1].
// Sequence length >= 512, so bool-bytes give m8[1]==1; int32 gives 0 (high
// byte of element 0). Mask is a prefix mask, so len == popcount(nonzero).
// ---------------------------------------------------------------------------

// K2: Viterbi forward, value-only max. One block (4 waves) per batch.
// Wave w owns cp-window [32w,32w+32). Lane l computes candidates for
// cc0=l, cc1=l+64 over its wave's cp window; partial maxes combined in LDS;
// owner lane (i<32 of wave w, cc=32w+i) finalizes s[cc]=max+emis and keeps it
// in-register so next step's readlane broadcast is wave-local. One barrier
// per step (double-buffered partials). Score row l overwrites emis row l
// IN PLACE (emis row l is consumed strictly before: prefetch reads row l+1).
__global__ __launch_bounds__(256) void k_forward(float* __restrict__ emis,
                                                 const unsigned char* __restrict__ mask,
                                                 const float* __restrict__ T) {
    const int b    = blockIdx.x;
    const int tid  = threadIdx.x;
    const int w    = tid >> 6;
    const int lane = tid & 63;

    __shared__ float part[2][128][4];
    __shared__ int s_len;
    if (tid == 0) s_len = 0;
    __syncthreads();

    // sequence length
    {
        const bool is_b8 = (mask[1] != 0);
        int c;
        if (is_b8) {
            const uchar4* m4 = (const uchar4*)(mask + (size_t)b * LL);
            uchar4 mv = m4[tid];
            c = (mv.x != 0) + (mv.y != 0) + (mv.z != 0) + (mv.w != 0);
        } else {
            const int4* m4 = (const int4*)((const int*)(const void*)mask + (size_t)b * LL);
            int4 mv = m4[tid];
            c = (mv.x != 0) + (mv.y != 0) + (mv.z != 0) + (mv.w != 0);
        }
        atomicAdd(&s_len, c);
    }
    __syncthreads();
    const int len = s_len;

    // T columns for this lane over the wave's cp window, in registers
    float t0[32], t1[32];
#pragma unroll
    for (int j = 0; j < 32; ++j) {
        t0[j] = T[(size_t)(w * 32 + j) * CC + lane];
        t1[j] = T[(size_t)(w * 32 + j) * CC + lane + 64];
    }

    const int cc_own = w * 32 + (lane & 31);
    float* eb = emis + (size_t)b * LL * CC;   // emis rows become score rows in place

    float s_val = 0.0f;                      // s[cc_own] for owner lanes
    float e_cur = eb[cc_own];                // emis row 0

    for (int l = 0; l < len; ++l) {
        int ln = l + 1 < len ? l + 1 : len - 1;
        float e_nxt = eb[(size_t)ln * CC + cc_own];   // prefetch next emis row

        float acc0 = -INFINITY, acc1 = -INFINITY;
#pragma unroll
        for (int jj = 0; jj < 16; ++jj) {
            float sa = __int_as_float(__builtin_amdgcn_readlane(__float_as_int(s_val), 2 * jj));
            float sb = __int_as_float(__builtin_amdgcn_readlane(__float_as_int(s_val), 2 * jj + 1));
            acc0 = fmaxf(fmaxf(sa + t0[2 * jj], sb + t0[2 * jj + 1]), acc0);
            acc1 = fmaxf(fmaxf(sa + t1[2 * jj], sb + t1[2 * jj + 1]), acc1);
        }
        int p = l & 1;
        part[p][lane][w]      = acc0;
        part[p][lane + 64][w] = acc1;
        __syncthreads();
        if (lane < 32) {
            float4 pv = *(const float4*)&part[p][cc_own][0];
            float mx = fmaxf(fmaxf(pv.x, pv.y), fmaxf(pv.z, pv.w));
            s_val = mx + e_cur;
            eb[(size_t)l * CC + cc_own] = s_val;   // overwrite emis row l with s row l
        }
        e_cur = e_nxt;
    }
}

// ---------------------------------------------------------------------------
// K3: backtrack. One wave per batch. Recompute the single needed argmax per
// step from stored scores + T column (exact first-index tie-break via
// monotonic-u32 keys, DPP max reduction, ballot+ctz).
// ---------------------------------------------------------------------------
__device__ __forceinline__ unsigned mono_u32(float f) {
    unsigned u = __float_as_uint(f);
    return u ^ (unsigned)(((int)u >> 31) | 0x80000000);
}

__device__ __forceinline__ unsigned dpp_max64(unsigned m) {
    unsigned t;
    t = (unsigned)__builtin_amdgcn_update_dpp(0, (int)m, 0x111, 0xF, 0xF, true); m = m > t ? m : t;
    t = (unsigned)__builtin_amdgcn_update_dpp(0, (int)m, 0x112, 0xF, 0xF, true); m = m > t ? m : t;
    t = (unsigned)__builtin_amdgcn_update_dpp(0, (int)m, 0x114, 0xF, 0xF, true); m = m > t ? m : t;
    t = (unsigned)__builtin_amdgcn_update_dpp(0, (int)m, 0x118, 0xF, 0xF, true); m = m > t ? m : t;
    t = (unsigned)__builtin_amdgcn_update_dpp(0, (int)m, 0x142, 0xF, 0xF, true); m = m > t ? m : t;
    t = (unsigned)__builtin_amdgcn_update_dpp(0, (int)m, 0x143, 0xF, 0xF, true); m = m > t ? m : t;
    return m;   // lane 63 holds the wave max
}

// argmax_cp( sA/sB + T_t[row][cp] ), cp0 = lane, cp1 = lane+64, first index wins
__device__ __forceinline__ int astep(float sA, float sB, int row,
                                     const float* ldsT, int lane) {
    int q = (row & 7) << 2;                     // XOR swizzle (16B blocks)
    float c0 = sA + ldsT[row * CC + (lane ^ q)];
    float c1 = sB + ldsT[row * CC + ((lane ^ q) + 64)];
    unsigned m0 = mono_u32(c0), m1 = mono_u32(c1);
    unsigned m = m0 > m1 ? m0 : m1;
    m = dpp_max64(m);
    unsigned mx = (unsigned)__builtin_amdgcn_readlane((int)m, 63);
    unsigned long long bl0 = __ballot(m0 == mx);
    unsigned long long bl1 = __ballot(m1 == mx);
    return bl0 ? __builtin_ctzll(bl0) : (64 + __builtin_ctzll(bl1));
}

__global__ __launch_bounds__(64) void k_back(const float* __restrict__ slog,
                                             const unsigned char* __restrict__ mask,
                                             const float* __restrict__ T,
                                             int* __restrict__ out) {
    const int b    = blockIdx.x;
    const int lane = threadIdx.x;
    __shared__ float ldsT[CC * CC];   // T transposed: ldsT[cc][cp], XOR-swizzled

    // stage T transposed (coalesced global reads, swizzled LDS writes)
    {
        int q = (lane & 7) << 2;
        for (int r = 0; r < CC; ++r) {
            float v0 = T[(size_t)r * CC + lane];
            float v1 = T[(size_t)r * CC + lane + 64];
            ldsT[lane * CC + (r ^ q)]        = v0;
            ldsT[(lane + 64) * CC + (r ^ q)] = v1;
        }
    }
    // sequence length via ballots
    int len = 0;
    {
        const bool is_b8 = (mask[1] != 0);
        if (is_b8) {
            const unsigned char* mrow = mask + (size_t)b * LL;
            for (int i = 0; i < 16; ++i)
                len += (int)__popcll(__ballot(mrow[lane + i * 64] != 0));
        } else {
            const int* mrow = (const int*)(const void*)mask + (size_t)b * LL;
            for (int i = 0; i < 16; ++i)
                len += (int)__popcll(__ballot(mrow[lane + i * 64] != 0));
        }
    }
    __syncthreads();

    const float* sb = slog + (size_t)b * LL * CC;
    int* ob         = out + (size_t)b * LL;

    // zero-fill beyond the sequence
    for (int l = len + lane; l < LL; l += 64) ob[l] = 0;

    // last tag: argmax_c( s_final[c] + T[c][STOP] )
    float f0 = sb[(size_t)(len - 1) * CC + lane];
    float f1 = sb[(size_t)(len - 1) * CC + lane + 64];
    int cur = astep(f0, f1, STOPTAG, ldsT, lane);
    if (lane == 0) ob[len - 1] = cur;

    // walk r = len-2 .. 0 :  cur = argmax(slog[r] + T[:,cur]); out[r] = cur
    int r = len - 2;                       // len >= 512, so r >= 1 here
    float a0 = sb[(size_t)r * CC + lane];
    float a1 = sb[(size_t)r * CC + lane + 64];
    float b0 = sb[(size_t)(r - 1) * CC + lane];
    float b1 = sb[(size_t)(r - 1) * CC + lane + 64];
    while (r >= 2) {
        int rc = r - 2;
        int rd = r - 3 >= 0 ? r - 3 : 0;
        float n0 = sb[(size_t)rc * CC + lane];
        float n1 = sb[(size_t)rc * CC + lane + 64];
        float p0 = sb[(size_t)rd * CC + lane];
        float p1 = sb[(size_t)rd * CC + lane + 64];
        cur = astep(a0, a1, cur, ldsT, lane);
        if (lane == 0) ob[r] = cur;
        cur = astep(b0, b1, cur, ldsT, lane);
        if (lane == 0) ob[r - 1] = cur;
        a0 = n0; a1 = n1; b0 = p0; b1 = p1;
        r -= 2;
    }
    if (r == 1) {
        cur = astep(a0, a1, cur, ldsT, lane);
        if (lane == 0) ob[1] = cur;
        cur = astep(b0, b1, cur, ldsT, lane);
        if (lane == 0) ob[0] = cur;
    } else if (r == 0) {
        cur = astep(a0, a1, cur, ldsT, lane);
        if (lane == 0) ob[0] = cur;
    }
}

// ---------------------------------------------------------------------------
extern "C" void kernel_launch(void* const* d_in, const int* in_sizes, int n_in,
                              void* d_out, int out_size, void* d_ws, size_t ws_size,
                              hipStream_t stream) {
    (void)in_sizes; (void)n_in; (void)out_size; (void)ws_size;
    const float* x    = (const float*)d_in[0];
    const unsigned char* mask = (const unsigned char*)d_in[1];
    // d_in[2] = y (unused by the reference output)
    const float* W    = (const float*)d_in[3];
    const float* bias = (const float*)d_in[4];
    const float* T    = (const float*)d_in[5];
    int* out = (int*)d_out;

    float* emis = (float*)d_ws;   // 32 MB; score rows overwrite emis in place

    k_emis<<<dim3(512), dim3(256), 0, stream>>>(x, W, bias, emis);
    k_forward<<<dim3(BB), dim3(256), 0, stream>>>(emis, mask, T);
    k_back<<<dim3(BB), dim3(64), 0, stream>>>(emis, mask, T, out);
}

// Round 4
// 1345.031 us; speedup vs baseline: 1.0134x; 1.0134x over previous
//
#include <hip/hip_runtime.h>
#include <stdint.h>

// Problem constants
#define BB 64
#define LL 1024
#define DD 1024
#define CC 128
#define STOPTAG 127

// ---------------------------------------------------------------------------
// K1: emis[b*L + l][c] = sum_k x[.][k] * W[k][c] + bias[c]   (pure f32)
// Tile: 128 rows x 128 cols per block, BK=32, 256 threads, 8x8 micro-tile.
// ---------------------------------------------------------------------------
__global__ __launch_bounds__(256) void k_emis(const float* __restrict__ x,
                                              const float* __restrict__ W,
                                              const float* __restrict__ bias,
                                              float* __restrict__ emis) {
    __shared__ float a_t[32][132];   // [k][row], stride 132 -> 528B rows (16B aligned)
    const int tid = threadIdx.x;
    const int bm  = blockIdx.x;                  // block of 128 rows
    const float* A = x + (size_t)bm * 128 * DD;
    const int tx = tid & 15, ty = tid >> 4;
    const int r0 = ty * 8, c0 = tx * 8;

    float acc[8][8];
#pragma unroll
    for (int i = 0; i < 8; ++i)
#pragma unroll
        for (int j = 0; j < 8; ++j) acc[i][j] = 0.0f;

    for (int kc = 0; kc < 32; ++kc) {
        __syncthreads();   // WAR on a_t
#pragma unroll
        for (int i = 0; i < 4; ++i) {
            int s   = tid + 256 * i;
            int row = s >> 3;
            int k0  = (s & 7) * 4;
            float4 v = *(const float4*)(A + (size_t)row * DD + kc * 32 + k0);
            a_t[k0 + 0][row] = v.x;
            a_t[k0 + 1][row] = v.y;
            a_t[k0 + 2][row] = v.z;
            a_t[k0 + 3][row] = v.w;
        }
        __syncthreads();
        const float* Wp = W + (size_t)kc * 32 * CC;
#pragma unroll
        for (int k = 0; k < 32; ++k) {
            float4 w0 = *(const float4*)(Wp + k * CC + c0);
            float4 w1 = *(const float4*)(Wp + k * CC + c0 + 4);
            float4 pa = *(const float4*)&a_t[k][r0];
            float4 pb = *(const float4*)&a_t[k][r0 + 4];
            float av[8] = {pa.x, pa.y, pa.z, pa.w, pb.x, pb.y, pb.z, pb.w};
            float wv[8] = {w0.x, w0.y, w0.z, w0.w, w1.x, w1.y, w1.z, w1.w};
#pragma unroll
            for (int i = 0; i < 8; ++i)
#pragma unroll
                for (int j = 0; j < 8; ++j)
                    acc[i][j] = fmaf(av[i], wv[j], acc[i][j]);
        }
    }
    float4 bv0 = *(const float4*)(bias + c0);
    float4 bv1 = *(const float4*)(bias + c0 + 4);
    float bb[8] = {bv0.x, bv0.y, bv0.z, bv0.w, bv1.x, bv1.y, bv1.z, bv1.w};
#pragma unroll
    for (int i = 0; i < 8; ++i) {
        size_t row = (size_t)bm * 128 + r0 + i;
        float4 o0 = make_float4(acc[i][0] + bb[0], acc[i][1] + bb[1],
                                acc[i][2] + bb[2], acc[i][3] + bb[3]);
        float4 o1 = make_float4(acc[i][4] + bb[4], acc[i][5] + bb[5],
                                acc[i][6] + bb[6], acc[i][7] + bb[7]);
        *(float4*)(emis + row * CC + c0)     = o0;
        *(float4*)(emis + row * CC + c0 + 4) = o1;
    }
}

// ---------------------------------------------------------------------------
// Mask may arrive as 1-byte bool or widened int32. Discriminator: byte [1]
// (len >= 512 so bool-bytes give mask[1]==1; int32 gives 0).
// ---------------------------------------------------------------------------

// K2: Viterbi forward, value-only max. One block (4 waves) per batch.
// Raw s_barrier + lgkmcnt-only wait in the step loop: emis prefetch loads
// (2 rows ahead) and score stores stay IN FLIGHT across barriers — no
// per-step vmcnt(0) drain (that drain was ~70% of round-3's step time).
// part[2][4][128]: writes stride-4B, owner reads 32-consecutive -> conflict-free.
// Score row l overwrites emis row l in place (emis row consumed strictly before).
__global__ __launch_bounds__(256) void k_forward(float* __restrict__ emis,
                                                 const unsigned char* __restrict__ mask,
                                                 const float* __restrict__ T) {
    const int b    = blockIdx.x;
    const int tid  = threadIdx.x;
    const int w    = tid >> 6;
    const int lane = tid & 63;

    __shared__ float part[2][4][CC];
    __shared__ int s_len;
    if (tid == 0) s_len = 0;
    __syncthreads();

    // sequence length (prefix mask -> popcount)
    {
        const bool is_b8 = (mask[1] != 0);
        int c;
        if (is_b8) {
            const uchar4* m4 = (const uchar4*)(mask + (size_t)b * LL);
            uchar4 mv = m4[tid];
            c = (mv.x != 0) + (mv.y != 0) + (mv.z != 0) + (mv.w != 0);
        } else {
            const int4* m4 = (const int4*)((const int*)(const void*)mask + (size_t)b * LL);
            int4 mv = m4[tid];
            c = (mv.x != 0) + (mv.y != 0) + (mv.z != 0) + (mv.w != 0);
        }
        atomicAdd(&s_len, c);
    }
    __syncthreads();
    const int len = s_len;

    // T columns for this lane over the wave's cp window, in registers
    float t0[32], t1[32];
#pragma unroll
    for (int j = 0; j < 32; ++j) {
        t0[j] = T[(size_t)(w * 32 + j) * CC + lane];
        t1[j] = T[(size_t)(w * 32 + j) * CC + lane + 64];
    }

    const int cc_own = w * 32 + (lane & 31);
    float* eb = emis + (size_t)b * LL * CC;   // emis rows become score rows in place

    float s_val = 0.0f;                       // s[cc_own] for owner lanes (0..31)
    float e_cur = eb[cc_own];                 // emis row 0
    float e_n1  = eb[CC + cc_own];            // emis row 1 (len >= 512)

    for (int l = 0; l < len; ++l) {
        int lp = l + 2 < len ? l + 2 : len - 1;
        float e_n2 = eb[(size_t)lp * CC + cc_own];   // prefetch 2 ahead, stays in flight

        float acc0 = -INFINITY, acc1 = -INFINITY;
#pragma unroll
        for (int jj = 0; jj < 16; ++jj) {
            float sa = __int_as_float(__builtin_amdgcn_readlane(__float_as_int(s_val), 2 * jj));
            float sb = __int_as_float(__builtin_amdgcn_readlane(__float_as_int(s_val), 2 * jj + 1));
            acc0 = fmaxf(fmaxf(sa + t0[2 * jj], sb + t0[2 * jj + 1]), acc0);
            acc1 = fmaxf(fmaxf(sa + t1[2 * jj], sb + t1[2 * jj + 1]), acc1);
        }
        int p = l & 1;
        part[p][w][lane]      = acc0;
        part[p][w][lane + 64] = acc1;
        asm volatile("s_waitcnt lgkmcnt(0)" ::: "memory");  // LDS writes visible
        __builtin_amdgcn_s_barrier();                        // raw: vmem stays in flight
        if (lane < 32) {
            float p0 = part[p][0][cc_own];
            float p1 = part[p][1][cc_own];
            float p2 = part[p][2][cc_own];
            float p3 = part[p][3][cc_own];
            float mx = fmaxf(fmaxf(p0, p1), fmaxf(p2, p3));
            s_val = mx + e_cur;
            eb[(size_t)l * CC + cc_own] = s_val;   // overwrite emis row l with s row l
        }
        e_cur = e_n1;
        e_n1  = e_n2;
    }
}

// ---------------------------------------------------------------------------
// K3: backtrack. One wave per batch. Exact first-index argmax per step
// (monotonic-u32 keys, DPP max reduction, ballot+ctz).
// ---------------------------------------------------------------------------
__device__ __forceinline__ unsigned mono_u32(float f) {
    unsigned u = __float_as_uint(f);
    return u ^ (unsigned)(((int)u >> 31) | 0x80000000);
}

__device__ __forceinline__ unsigned dpp_max64(unsigned m) {
    unsigned t;
    t = (unsigned)__builtin_amdgcn_update_dpp(0, (int)m, 0x111, 0xF, 0xF, true); m = m > t ? m : t;
    t = (unsigned)__builtin_amdgcn_update_dpp(0, (int)m, 0x112, 0xF, 0xF, true); m = m > t ? m : t;
    t = (unsigned)__builtin_amdgcn_update_dpp(0, (int)m, 0x114, 0xF, 0xF, true); m = m > t ? m : t;
    t = (unsigned)__builtin_amdgcn_update_dpp(0, (int)m, 0x118, 0xF, 0xF, true); m = m > t ? m : t;
    t = (unsigned)__builtin_amdgcn_update_dpp(0, (int)m, 0x142, 0xF, 0xF, true); m = m > t ? m : t;
    t = (unsigned)__builtin_amdgcn_update_dpp(0, (int)m, 0x143, 0xF, 0xF, true); m = m > t ? m : t;
    return m;   // lane 63 holds the wave max
}

// argmax_cp( sA/sB + T_t[row][cp] ), cp0 = lane, cp1 = lane+64, first index wins
__device__ __forceinline__ int astep(float sA, float sB, int row,
                                     const float* ldsT, int lane) {
    int q = (row & 7) << 2;                     // XOR swizzle (16B blocks)
    float c0 = sA + ldsT[row * CC + (lane ^ q)];
    float c1 = sB + ldsT[row * CC + ((lane ^ q) + 64)];
    unsigned m0 = mono_u32(c0), m1 = mono_u32(c1);
    unsigned m = m0 > m1 ? m0 : m1;
    m = dpp_max64(m);
    unsigned mx = (unsigned)__builtin_amdgcn_readlane((int)m, 63);
    unsigned long long bl0 = __ballot(m0 == mx);
    unsigned long long bl1 = __ballot(m1 == mx);
    return bl0 ? __builtin_ctzll(bl0) : (64 + __builtin_ctzll(bl1));
}

__global__ __launch_bounds__(64) void k_back(const float* __restrict__ slog,
                                             const unsigned char* __restrict__ mask,
                                             const float* __restrict__ T,
                                             int* __restrict__ out) {
    const int b    = blockIdx.x;
    const int lane = threadIdx.x;
    __shared__ float ldsT[CC * CC];   // T transposed: ldsT[cc][cp], XOR-swizzled

    {
        int q = (lane & 7) << 2;
        for (int r = 0; r < CC; ++r) {
            float v0 = T[(size_t)r * CC + lane];
            float v1 = T[(size_t)r * CC + lane + 64];
            ldsT[lane * CC + (r ^ q)]        = v0;
            ldsT[(lane + 64) * CC + (r ^ q)] = v1;
        }
    }
    // sequence length via ballots
    int len = 0;
    {
        const bool is_b8 = (mask[1] != 0);
        if (is_b8) {
            const unsigned char* mrow = mask + (size_t)b * LL;
            for (int i = 0; i < 16; ++i)
                len += (int)__popcll(__ballot(mrow[lane + i * 64] != 0));
        } else {
            const int* mrow = (const int*)(const void*)mask + (size_t)b * LL;
            for (int i = 0; i < 16; ++i)
                len += (int)__popcll(__ballot(mrow[lane + i * 64] != 0));
        }
    }
    __syncthreads();

    const float* sb = slog + (size_t)b * LL * CC;
    int* ob         = out + (size_t)b * LL;

    // zero-fill beyond the sequence
    for (int l = len + lane; l < LL; l += 64) ob[l] = 0;

    // last tag: argmax_c( s_final[c] + T[c][STOP] )
    float f0 = sb[(size_t)(len - 1) * CC + lane];
    float f1 = sb[(size_t)(len - 1) * CC + lane + 64];
    int cur = astep(f0, f1, STOPTAG, ldsT, lane);
    if (lane == 0) ob[len - 1] = cur;

    // walk r = len-2 .. 0 :  cur = argmax(slog[r] + T[:,cur]); out[r] = cur
    int r = len - 2;                       // len >= 512, so r >= 1 here
    float a0 = sb[(size_t)r * CC + lane];
    float a1 = sb[(size_t)r * CC + lane + 64];
    float b0 = sb[(size_t)(r - 1) * CC + lane];
    float b1 = sb[(size_t)(r - 1) * CC + lane + 64];
    while (r >= 2) {
        int rc = r - 2;
        int rd = r - 3 >= 0 ? r - 3 : 0;
        float n0 = sb[(size_t)rc * CC + lane];
        float n1 = sb[(size_t)rc * CC + lane + 64];
        float p0 = sb[(size_t)rd * CC + lane];
        float p1 = sb[(size_t)rd * CC + lane + 64];
        cur = astep(a0, a1, cur, ldsT, lane);
        if (lane == 0) ob[r] = cur;
        cur = astep(b0, b1, cur, ldsT, lane);
        if (lane == 0) ob[r - 1] = cur;
        a0 = n0; a1 = n1; b0 = p0; b1 = p1;
        r -= 2;
    }
    if (r == 1) {
        cur = astep(a0, a1, cur, ldsT, lane);
        if (lane == 0) ob[1] = cur;
        cur = astep(b0, b1, cur, ldsT, lane);
        if (lane == 0) ob[0] = cur;
    } else if (r == 0) {
        cur = astep(a0, a1, cur, ldsT, lane);
        if (lane == 0) ob[0] = cur;
    }
}

// ---------------------------------------------------------------------------
extern "C" void kernel_launch(void* const* d_in, const int* in_sizes, int n_in,
                              void* d_out, int out_size, void* d_ws, size_t ws_size,
                              hipStream_t stream) {
    (void)in_sizes; (void)n_in; (void)out_size; (void)ws_size;
    const float* x    = (const float*)d_in[0];
    const unsigned char* mask = (const unsigned char*)d_in[1];
    // d_in[2] = y (unused by the reference output)
    const float* W    = (const float*)d_in[3];
    const float* bias = (const float*)d_in[4];
    const float* T    = (const float*)d_in[5];
    int* out = (int*)d_out;

    float* emis = (float*)d_ws;   // 32 MB; score rows overwrite emis in place

    k_emis<<<dim3(512), dim3(256), 0, stream>>>(x, W, bias, emis);
    k_forward<<<dim3(BB), dim3(256), 0, stream>>>(emis, mask, T);
    k_back<<<dim3(BB), dim3(64), 0, stream>>>(emis, mask, T, out);
}

// Round 5
// 1295.755 us; speedup vs baseline: 1.0519x; 1.0380x over previous
//
#include <hip/hip_runtime.h>
#include <stdint.h>

// Problem constants
#define BB 64
#define LL 1024
#define DD 1024
#define CC 128
#define STOPTAG 127

// ---------------------------------------------------------------------------
// K1: emis[b*L + l][c] = sum_k x[.][k] * W[k][c] + bias[c]   (pure f32)
// Tile: 128 rows x 128 cols per block, BK=32, 256 threads, 8x8 micro-tile.
// ---------------------------------------------------------------------------
__global__ __launch_bounds__(256) void k_emis(const float* __restrict__ x,
                                              const float* __restrict__ W,
                                              const float* __restrict__ bias,
                                              float* __restrict__ emis) {
    __shared__ float a_t[32][132];   // [k][row], stride 132 -> 528B rows (16B aligned)
    const int tid = threadIdx.x;
    const int bm  = blockIdx.x;                  // block of 128 rows
    const float* A = x + (size_t)bm * 128 * DD;
    const int tx = tid & 15, ty = tid >> 4;
    const int r0 = ty * 8, c0 = tx * 8;

    float acc[8][8];
#pragma unroll
    for (int i = 0; i < 8; ++i)
#pragma unroll
        for (int j = 0; j < 8; ++j) acc[i][j] = 0.0f;

    for (int kc = 0; kc < 32; ++kc) {
        __syncthreads();   // WAR on a_t
#pragma unroll
        for (int i = 0; i < 4; ++i) {
            int s   = tid + 256 * i;
            int row = s >> 3;
            int k0  = (s & 7) * 4;
            float4 v = *(const float4*)(A + (size_t)row * DD + kc * 32 + k0);
            a_t[k0 + 0][row] = v.x;
            a_t[k0 + 1][row] = v.y;
            a_t[k0 + 2][row] = v.z;
            a_t[k0 + 3][row] = v.w;
        }
        __syncthreads();
        const float* Wp = W + (size_t)kc * 32 * CC;
#pragma unroll
        for (int k = 0; k < 32; ++k) {
            float4 w0 = *(const float4*)(Wp + k * CC + c0);
            float4 w1 = *(const float4*)(Wp + k * CC + c0 + 4);
            float4 pa = *(const float4*)&a_t[k][r0];
            float4 pb = *(const float4*)&a_t[k][r0 + 4];
            float av[8] = {pa.x, pa.y, pa.z, pa.w, pb.x, pb.y, pb.z, pb.w};
            float wv[8] = {w0.x, w0.y, w0.z, w0.w, w1.x, w1.y, w1.z, w1.w};
#pragma unroll
            for (int i = 0; i < 8; ++i)
#pragma unroll
                for (int j = 0; j < 8; ++j)
                    acc[i][j] = fmaf(av[i], wv[j], acc[i][j]);
        }
    }
    float4 bv0 = *(const float4*)(bias + c0);
    float4 bv1 = *(const float4*)(bias + c0 + 4);
    float bb[8] = {bv0.x, bv0.y, bv0.z, bv0.w, bv1.x, bv1.y, bv1.z, bv1.w};
#pragma unroll
    for (int i = 0; i < 8; ++i) {
        size_t row = (size_t)bm * 128 + r0 + i;
        float4 o0 = make_float4(acc[i][0] + bb[0], acc[i][1] + bb[1],
                                acc[i][2] + bb[2], acc[i][3] + bb[3]);
        float4 o1 = make_float4(acc[i][4] + bb[4], acc[i][5] + bb[5],
                                acc[i][6] + bb[6], acc[i][7] + bb[7]);
        *(float4*)(emis + row * CC + c0)     = o0;
        *(float4*)(emis + row * CC + c0 + 4) = o1;
    }
}

// ---------------------------------------------------------------------------
// Mask may arrive as 1-byte bool or widened int32. Discriminator: byte [1]
// (len >= 512 so bool-bytes give mask[1]==1; int32 gives 0).
// ---------------------------------------------------------------------------

// K2: Viterbi forward. 8 waves per batch (512 threads), wave w owns the
// 16-wide cp window [16w,16w+16). 2 waves/SIMD so LDS/barrier stalls of one
// wave hide under the other's issue (round-4 profile: 1 wave/SIMD left
// ~760 cy/step of exposed latency, VALUBusy 34% on active CUs).
// Lane l: candidates for cc0=l, cc1=l+64 over its wave's window (16 readlanes,
// T window in 32 VGPRs). Partials -> part[l&1][w][cc] (conflict-free), raw
// s_barrier + lgkmcnt-only wait (global loads/stores stay in flight, never
// vmcnt-drained). ALL lanes redundantly finalize cc=16w+(lane&15): 8 ds_reads
// (16 consecutive floats, 4-way same-address -> broadcast), no exec-mask
// churn; duplicate same-value global stores are benign.
// Score row l overwrites emis row l in place (row consumed strictly before).
__global__ __launch_bounds__(512) void k_forward(float* __restrict__ emis,
                                                 const unsigned char* __restrict__ mask,
                                                 const float* __restrict__ T) {
    const int b    = blockIdx.x;
    const int tid  = threadIdx.x;
    const int w    = tid >> 6;
    const int lane = tid & 63;

    __shared__ float part[2][8][CC];
    __shared__ int s_len;
    if (tid == 0) s_len = 0;
    __syncthreads();

    // sequence length (prefix mask -> popcount); 256 threads cover 1024 elems
    if (tid < 256) {
        const bool is_b8 = (mask[1] != 0);
        int c;
        if (is_b8) {
            const uchar4* m4 = (const uchar4*)(mask + (size_t)b * LL);
            uchar4 mv = m4[tid];
            c = (mv.x != 0) + (mv.y != 0) + (mv.z != 0) + (mv.w != 0);
        } else {
            const int4* m4 = (const int4*)((const int*)(const void*)mask + (size_t)b * LL);
            int4 mv = m4[tid];
            c = (mv.x != 0) + (mv.y != 0) + (mv.z != 0) + (mv.w != 0);
        }
        atomicAdd(&s_len, c);
    }
    __syncthreads();
    const int len = s_len;

    // T columns for this lane over the wave's 16-wide cp window
    float t0[16], t1[16];
#pragma unroll
    for (int j = 0; j < 16; ++j) {
        t0[j] = T[(size_t)(w * 16 + j) * CC + lane];
        t1[j] = T[(size_t)(w * 16 + j) * CC + lane + 64];
    }

    const int cc_fin = w * 16 + (lane & 15);  // tag this lane finalizes
    float* eb = emis + (size_t)b * LL * CC;   // emis rows become score rows in place

    float s_val = 0.0f;                       // s[cc_fin] (valid in lanes 0..15 for readlane)
    float e_cur = eb[cc_fin];                 // emis row 0
    float e_n1  = eb[CC + cc_fin];            // emis row 1 (len >= 512)

    for (int l = 0; l < len; ++l) {
        int lp = l + 2 < len ? l + 2 : len - 1;
        float e_n2 = eb[(size_t)lp * CC + cc_fin];   // prefetch 2 ahead, stays in flight

        float acc0 = -INFINITY, acc1 = -INFINITY;
#pragma unroll
        for (int jj = 0; jj < 8; ++jj) {
            float sa = __int_as_float(__builtin_amdgcn_readlane(__float_as_int(s_val), 2 * jj));
            float sb = __int_as_float(__builtin_amdgcn_readlane(__float_as_int(s_val), 2 * jj + 1));
            acc0 = fmaxf(fmaxf(sa + t0[2 * jj], sb + t0[2 * jj + 1]), acc0);
            acc1 = fmaxf(fmaxf(sa + t1[2 * jj], sb + t1[2 * jj + 1]), acc1);
        }
        int p = l & 1;
        part[p][w][lane]      = acc0;
        part[p][w][lane + 64] = acc1;
        asm volatile("s_waitcnt lgkmcnt(0)" ::: "memory");  // LDS writes visible
        __builtin_amdgcn_s_barrier();                        // raw: vmem stays in flight
        float m0 = fmaxf(part[p][0][cc_fin], part[p][1][cc_fin]);
        float m1 = fmaxf(part[p][2][cc_fin], part[p][3][cc_fin]);
        float m2 = fmaxf(part[p][4][cc_fin], part[p][5][cc_fin]);
        float m3 = fmaxf(part[p][6][cc_fin], part[p][7][cc_fin]);
        float mx = fmaxf(fmaxf(m0, m1), fmaxf(m2, m3));
        s_val = mx + e_cur;
        eb[(size_t)l * CC + cc_fin] = s_val;   // 4-way duplicate store, same value
        e_cur = e_n1;
        e_n1  = e_n2;
    }
}

// ---------------------------------------------------------------------------
// K3: backtrack. One wave per batch. Exact first-index argmax per step
// (monotonic-u32 keys, DPP max reduction, ballot+ctz).
// ---------------------------------------------------------------------------
__device__ __forceinline__ unsigned mono_u32(float f) {
    unsigned u = __float_as_uint(f);
    return u ^ (unsigned)(((int)u >> 31) | 0x80000000);
}

__device__ __forceinline__ unsigned dpp_max64(unsigned m) {
    unsigned t;
    t = (unsigned)__builtin_amdgcn_update_dpp(0, (int)m, 0x111, 0xF, 0xF, true); m = m > t ? m : t;
    t = (unsigned)__builtin_amdgcn_update_dpp(0, (int)m, 0x112, 0xF, 0xF, true); m = m > t ? m : t;
    t = (unsigned)__builtin_amdgcn_update_dpp(0, (int)m, 0x114, 0xF, 0xF, true); m = m > t ? m : t;
    t = (unsigned)__builtin_amdgcn_update_dpp(0, (int)m, 0x118, 0xF, 0xF, true); m = m > t ? m : t;
    t = (unsigned)__builtin_amdgcn_update_dpp(0, (int)m, 0x142, 0xF, 0xF, true); m = m > t ? m : t;
    t = (unsigned)__builtin_amdgcn_update_dpp(0, (int)m, 0x143, 0xF, 0xF, true); m = m > t ? m : t;
    return m;   // lane 63 holds the wave max
}

// argmax_cp( sA/sB + T_t[row][cp] ), cp0 = lane, cp1 = lane+64, first index wins
__device__ __forceinline__ int astep(float sA, float sB, int row,
                                     const float* ldsT, int lane) {
    int q = (row & 7) << 2;                     // XOR swizzle (16B blocks)
    float c0 = sA + ldsT[row * CC + (lane ^ q)];
    float c1 = sB + ldsT[row * CC + ((lane ^ q) + 64)];
    unsigned m0 = mono_u32(c0), m1 = mono_u32(c1);
    unsigned m = m0 > m1 ? m0 : m1;
    m = dpp_max64(m);
    unsigned mx = (unsigned)__builtin_amdgcn_readlane((int)m, 63);
    unsigned long long bl0 = __ballot(m0 == mx);
    unsigned long long bl1 = __ballot(m1 == mx);
    return bl0 ? __builtin_ctzll(bl0) : (64 + __builtin_ctzll(bl1));
}

__global__ __launch_bounds__(64) void k_back(const float* __restrict__ slog,
                                             const unsigned char* __restrict__ mask,
                                             const float* __restrict__ T,
                                             int* __restrict__ out) {
    const int b    = blockIdx.x;
    const int lane = threadIdx.x;
    __shared__ float ldsT[CC * CC];   // T transposed: ldsT[cc][cp], XOR-swizzled

    {
        int q = (lane & 7) << 2;
        for (int r = 0; r < CC; ++r) {
            float v0 = T[(size_t)r * CC + lane];
            float v1 = T[(size_t)r * CC + lane + 64];
            ldsT[lane * CC + (r ^ q)]        = v0;
            ldsT[(lane + 64) * CC + (r ^ q)] = v1;
        }
    }
    // sequence length via ballots
    int len = 0;
    {
        const bool is_b8 = (mask[1] != 0);
        if (is_b8) {
            const unsigned char* mrow = mask + (size_t)b * LL;
            for (int i = 0; i < 16; ++i)
                len += (int)__popcll(__ballot(mrow[lane + i * 64] != 0));
        } else {
            const int* mrow = (const int*)(const void*)mask + (size_t)b * LL;
            for (int i = 0; i < 16; ++i)
                len += (int)__popcll(__ballot(mrow[lane + i * 64] != 0));
        }
    }
    __syncthreads();

    const float* sb = slog + (size_t)b * LL * CC;
    int* ob         = out + (size_t)b * LL;

    // zero-fill beyond the sequence
    for (int l = len + lane; l < LL; l += 64) ob[l] = 0;

    // last tag: argmax_c( s_final[c] + T[c][STOP] )
    float f0 = sb[(size_t)(len - 1) * CC + lane];
    float f1 = sb[(size_t)(len - 1) * CC + lane + 64];
    int cur = astep(f0, f1, STOPTAG, ldsT, lane);
    if (lane == 0) ob[len - 1] = cur;

    // walk r = len-2 .. 0 :  cur = argmax(slog[r] + T[:,cur]); out[r] = cur
    int r = len - 2;                       // len >= 512, so r >= 1 here
    float a0 = sb[(size_t)r * CC + lane];
    float a1 = sb[(size_t)r * CC + lane + 64];
    float b0 = sb[(size_t)(r - 1) * CC + lane];
    float b1 = sb[(size_t)(r - 1) * CC + lane + 64];
    while (r >= 2) {
        int rc = r - 2;
        int rd = r - 3 >= 0 ? r - 3 : 0;
        float n0 = sb[(size_t)rc * CC + lane];
        float n1 = sb[(size_t)rc * CC + lane + 64];
        float p0 = sb[(size_t)rd * CC + lane];
        float p1 = sb[(size_t)rd * CC + lane + 64];
        cur = astep(a0, a1, cur, ldsT, lane);
        if (lane == 0) ob[r] = cur;
        cur = astep(b0, b1, cur, ldsT, lane);
        if (lane == 0) ob[r - 1] = cur;
        a0 = n0; a1 = n1; b0 = p0; b1 = p1;
        r -= 2;
    }
    if (r == 1) {
        cur = astep(a0, a1, cur, ldsT, lane);
        if (lane == 0) ob[1] = cur;
        cur = astep(b0, b1, cur, ldsT, lane);
        if (lane == 0) ob[0] = cur;
    } else if (r == 0) {
        cur = astep(a0, a1, cur, ldsT, lane);
        if (lane == 0) ob[0] = cur;
    }
}

// ---------------------------------------------------------------------------
extern "C" void kernel_launch(void* const* d_in, const int* in_sizes, int n_in,
                              void* d_out, int out_size, void* d_ws, size_t ws_size,
                              hipStream_t stream) {
    (void)in_sizes; (void)n_in; (void)out_size; (void)ws_size;
    const float* x    = (const float*)d_in[0];
    const unsigned char* mask = (const unsigned char*)d_in[1];
    // d_in[2] = y (unused by the reference output)
    const float* W    = (const float*)d_in[3];
    const float* bias = (const float*)d_in[4];
    const float* T    = (const float*)d_in[5];
    int* out = (int*)d_out;

    float* emis = (float*)d_ws;   // 32 MB; score rows overwrite emis in place

    k_emis<<<dim3(512), dim3(256), 0, stream>>>(x, W, bias, emis);
    k_forward<<<dim3(BB), dim3(512), 0, stream>>>(emis, mask, T);
    k_back<<<dim3(BB), dim3(64), 0, stream>>>(emis, mask, T, out);
}